// Round 3
// baseline (878.494 us; speedup 1.0000x reference)
//
#include <hip/hip_runtime.h>
#include <cstdint>

typedef __bf16 bf16;
typedef __attribute__((ext_vector_type(8))) __bf16 bf16x8;
typedef __attribute__((ext_vector_type(4))) __bf16 bf16x4;
typedef __attribute__((ext_vector_type(4))) float f32x4;
typedef __attribute__((ext_vector_type(2))) float f32x2;

static __device__ __forceinline__ float elu1(float x) {
    return x > 0.f ? x : (__expf(x) - 1.f);
}

// global -> LDS async copy, 16 B per lane.
static __device__ __forceinline__ void gl_lds16(const void* gp, void* lp) {
    __builtin_amdgcn_global_load_lds(
        (const __attribute__((address_space(1))) void*)(uintptr_t)gp,
        (__attribute__((address_space(3))) void*)(uint32_t)(uintptr_t)lp,
        16, 0, 0);
}

// ---------------------------------------------------------------------------
// Weight conversion: f32 -> bf16 concat, phi1_w1 rows padded 514 -> 576.
// ---------------------------------------------------------------------------
struct CvtArgs {
    const float* src[13];
    int rows[13];
    int scols[13];
    int dcols[13];
    int total;
};

__global__ void cvt_k(CvtArgs a, bf16* __restrict__ dst) {
    int idx = blockIdx.x * 256 + threadIdx.x;
    if (idx >= a.total) return;
    int rem = idx;
#pragma unroll 1
    for (int s = 0; s < 13; ++s) {
        int sz = a.rows[s] * a.dcols[s];
        if (rem < sz) {
            int r = rem / a.dcols[s];
            int c = rem - r * a.dcols[s];
            float v = (c < a.scols[s]) ? a.src[s][(long)r * a.scols[s] + c] : 0.f;
            dst[idx] = (bf16)v;
            return;
        }
        rem -= sz;
    }
}

// encA (65536 x 514 f32) -> bf16 padded to 576 cols. One thread = 8 cols.
__global__ void cvtA_k(const float* __restrict__ src, bf16* __restrict__ dst) {
    const int idx = blockIdx.x * 256 + threadIdx.x;
    const int row = idx / 72;
    const int c0 = (idx - row * 72) * 8;
    bf16x8 t;
    if (c0 + 8 <= 514) {
        const float* p = src + (long)row * 514 + c0;
#pragma unroll
        for (int e = 0; e < 8; e += 2) {
            f32x2 v = *(const f32x2*)(p + e);
            t[e] = (bf16)v.x; t[e + 1] = (bf16)v.y;
        }
    } else if (c0 < 514) {
        const float* p = src + (long)row * 514;
#pragma unroll
        for (int e = 0; e < 8; ++e)
            t[e] = (bf16)((c0 + e < 514) ? p[c0 + e] : 0.f);
    } else {
#pragma unroll
        for (int e = 0; e < 8; ++e) t[e] = (bf16)0.f;
    }
    *(bf16x8*)(dst + (long)row * 576 + c0) = t;
}

// Mbig[n][h*512+k] = sum_d Wout[n][h*256+d] * Wv_h[d][k]   (512 x 1024 bf16)
__global__ void mbig_k(const float* __restrict__ w_aout,
                       const float* __restrict__ w_ain,
                       bf16* __restrict__ M) {
    const int n = blockIdx.x;
    const int tid = threadIdx.x;
#pragma unroll 1
    for (int h = 0; h < 2; ++h) {
#pragma unroll 1
        for (int kc = 0; kc < 2; ++kc) {
            const int k = kc * 256 + tid;
            const float* ao = w_aout + (long)n * 512 + h * 256;
            const float* ai = w_ain + (long)(1024 + h * 256) * 512 + k;
            float acc = 0.f;
#pragma unroll 4
            for (int d = 0; d < 256; ++d)
                acc += ao[d] * ai[(long)d * 512];
            M[(long)n * 1024 + h * 512 + k] = (bf16)acc;
        }
    }
}

// c0[n] = sum_d b_ain[1024+d]*Wout[n][d] + b_aout[n]
__global__ void c0_k(const float* __restrict__ w_aout, const float* __restrict__ bv,
                     const float* __restrict__ bout, float* __restrict__ c0) {
    const int n = blockIdx.x * 128 + threadIdx.x;
    if (n >= 512) return;
    const float* wr = w_aout + (long)n * 512;
    float acc = 0.f;
    for (int d = 0; d < 512; ++d) acc += bv[d] * wr[d];
    c0[n] = acc + bout[n];
}

// ---------------------------------------------------------------------------
// Tiled GEMM (m97 structure): C = act(A @ W^T + bias)
// 128x128 tile, BK=64, 4 waves, 4x4 16x16x32 MFMA per wave.
// Swizzled LDS: 16B chunk s of row m at slot (s+m)&7 within the row.
// ---------------------------------------------------------------------------
struct GemmArgs {
    const float* Af;
    const bf16*  Ab;
    long lda;
    const float* enc;    // ALT mode
    const float* km;     // ALT mode
    const bf16*  key1;   // ALT mode
    const bf16*  W;
    long ldw;
    const float* bias;
    bf16*  Cb;
    float* Cf;
    long ldc;
    int nK;
};

enum { AM_F32 = 0, AM_BF16 = 2, AM_ALT = 3 };
enum { ACT_NONE = 0, ACT_ELU = 1, ACT_ELU2 = 2 };

template <int AMODE, int ACT, bool OUTB>
__global__ __launch_bounds__(256, 4) void gemm_t(GemmArgs g) {
    __shared__ bf16 As[128 * 64];
    __shared__ bf16 Bs[128 * 64];

    const int tid  = threadIdx.x;
    const int wave = tid >> 6;
    const int lane = tid & 63;
    const int ln   = lane & 15;
    const int quad = lane >> 4;

    const long m0 = (long)blockIdx.x * 128;
    const long n0 = (long)blockIdx.y * 128;
    const int  wm = (wave & 1) * 64;
    const int  wn = (wave >> 1) * 64;

    f32x4 acc[4][4] = {};

    for (int ks = 0; ks < g.nK; ++ks) {
        const int k0 = ks * 64;
        __syncthreads();

        // ---- stage A ----
        if constexpr (AMODE == AM_BF16) {
            const int cbase = wave * 256;
#pragma unroll
            for (int r = 0; r < 4; ++r) {
                const int c = cbase + r * 64 + lane;
                const int m = c >> 3, s = c & 7;
                const int pg = (s - m) & 7;
                gl_lds16(g.Ab + (m0 + m) * g.lda + k0 + pg * 8, &As[c * 8]);
            }
        } else {
#pragma unroll
            for (int r = 0; r < 4; ++r) {
                const int c = r * 256 + tid;
                const int m = c >> 3, s = c & 7;
                const int pg = (s - m) & 7;
                const int kk = k0 + pg * 8;
                bf16x8 t;
                if constexpr (AMODE == AM_F32) {
                    const float* ap = g.Af + (m0 + m) * g.lda + kk;
                    f32x4 p0 = *(const f32x4*)ap;
                    f32x4 p1 = *(const f32x4*)(ap + 4);
                    t[0] = (bf16)p0.x; t[1] = (bf16)p0.y; t[2] = (bf16)p0.z; t[3] = (bf16)p0.w;
                    t[4] = (bf16)p1.x; t[5] = (bf16)p1.y; t[6] = (bf16)p1.z; t[7] = (bf16)p1.w;
                } else {  // AM_ALT: enc + km[row/16] - key1/16
                    const long row = m0 + m;
                    const float* ep = g.enc + row * 512 + kk;
                    const float* mp = g.km + (row >> 4) * 512 + kk;
                    const bf16*  xp = g.key1 + row * 512 + kk;
                    f32x4 e0 = *(const f32x4*)ep;
                    f32x4 e1 = *(const f32x4*)(ep + 4);
                    f32x4 q0 = *(const f32x4*)mp;
                    f32x4 q1 = *(const f32x4*)(mp + 4);
                    bf16x8 x8 = *(const bf16x8*)xp;
                    t[0] = (bf16)(e0.x + q0.x - (float)x8[0] * 0.0625f);
                    t[1] = (bf16)(e0.y + q0.y - (float)x8[1] * 0.0625f);
                    t[2] = (bf16)(e0.z + q0.z - (float)x8[2] * 0.0625f);
                    t[3] = (bf16)(e0.w + q0.w - (float)x8[3] * 0.0625f);
                    t[4] = (bf16)(e1.x + q1.x - (float)x8[4] * 0.0625f);
                    t[5] = (bf16)(e1.y + q1.y - (float)x8[5] * 0.0625f);
                    t[6] = (bf16)(e1.z + q1.z - (float)x8[6] * 0.0625f);
                    t[7] = (bf16)(e1.w + q1.w - (float)x8[7] * 0.0625f);
                }
                *(bf16x8*)(&As[m * 64 + s * 8]) = t;
            }
        }

        // ---- stage B ----
        {
            const int cbase = wave * 256;
#pragma unroll
            for (int r = 0; r < 4; ++r) {
                const int c = cbase + r * 64 + lane;
                const int n = c >> 3, s = c & 7;
                const int pg = (s - n) & 7;
                gl_lds16(g.W + (n0 + n) * g.ldw + k0 + pg * 8, &Bs[c * 8]);
            }
        }
        __syncthreads();

        // ---- compute ----
#pragma unroll
        for (int ksub = 0; ksub < 2; ++ksub) {
            bf16x8 av[4], bv[4];
#pragma unroll
            for (int t = 0; t < 4; ++t) {
                const int m = wm + t * 16 + ln;
                const int sa = ((ksub * 4 + quad) + m) & 7;
                av[t] = *(const bf16x8*)(&As[m * 64 + sa * 8]);
                const int n = wn + t * 16 + ln;
                const int sb = ((ksub * 4 + quad) + n) & 7;
                bv[t] = *(const bf16x8*)(&Bs[n * 64 + sb * 8]);
            }
#pragma unroll
            for (int i = 0; i < 4; ++i)
#pragma unroll
                for (int j = 0; j < 4; ++j)
                    acc[i][j] = __builtin_amdgcn_mfma_f32_16x16x32_bf16(
                        av[i], bv[j], acc[i][j], 0, 0, 0);
        }
    }

    // ---- epilogue ----
#pragma unroll
    for (int i = 0; i < 4; ++i) {
        const long rb = m0 + wm + i * 16 + quad * 4;
#pragma unroll
        for (int j = 0; j < 4; ++j) {
            const long n = n0 + wn + j * 16 + ln;
            const float bvs = g.bias[n];
#pragma unroll
            for (int r = 0; r < 4; ++r) {
                float v = acc[i][j][r] + bvs;
                if constexpr (ACT >= ACT_ELU) v = elu1(v);
                if constexpr (ACT == ACT_ELU2) v = elu1(v);
                const long o = (rb + r) * g.ldc + n;
                if constexpr (OUTB) g.Cb[o] = (bf16)v;
                else                g.Cf[o] = v;
            }
        }
    }
}

// ---------------------------------------------------------------------------
// Attention v2: one wave per (group, head). QK buffer row = [q(512)|k(512)],
// head h at q: h*256, k: 512+h*256. Computes cbar = mean_i softmax rows,
// then y = cbar @ X (X = key1 group rows, 512 cols) -> Y[g][h*512..].
// ---------------------------------------------------------------------------
__global__ __launch_bounds__(256) void attn_k(const bf16* __restrict__ qk,
                                              const bf16* __restrict__ X,
                                              bf16* __restrict__ Y,
                                              int ngroups) {
    const int tid = blockIdx.x * 256 + threadIdx.x;
    const int wv = tid >> 6;
    const int g  = wv >> 1;
    const int h  = wv & 1;
    if (g >= ngroups) return;
    const int lane = threadIdx.x & 63;
    const int i  = lane & 15;
    const int jb = (lane >> 4) << 2;

    const bf16* base  = qk + (long)g * 16 * 1024;
    const bf16* qrow  = base + (long)i * 1024 + h * 256;
    const bf16* kbase = base + 512 + h * 256;

    float s0 = 0.f, s1 = 0.f, s2 = 0.f, s3 = 0.f;
    for (int kk = 0; kk < 256; kk += 8) {
        bf16x8 qv = *(const bf16x8*)(qrow + kk);
        float qf[8];
#pragma unroll
        for (int e = 0; e < 8; ++e) qf[e] = (float)qv[e];
        bf16x8 k0 = *(const bf16x8*)(kbase + (long)(jb + 0) * 1024 + kk);
        bf16x8 k1 = *(const bf16x8*)(kbase + (long)(jb + 1) * 1024 + kk);
        bf16x8 k2 = *(const bf16x8*)(kbase + (long)(jb + 2) * 1024 + kk);
        bf16x8 k3 = *(const bf16x8*)(kbase + (long)(jb + 3) * 1024 + kk);
#pragma unroll
        for (int e = 0; e < 8; ++e) {
            s0 += qf[e] * (float)k0[e];
            s1 += qf[e] * (float)k1[e];
            s2 += qf[e] * (float)k2[e];
            s3 += qf[e] * (float)k3[e];
        }
    }
    const float sc = 1.f / 16.f;  // 1/sqrt(256)
    s0 *= sc; s1 *= sc; s2 *= sc; s3 *= sc;
    float m = fmaxf(fmaxf(s0, s1), fmaxf(s2, s3));
    m = fmaxf(m, __shfl_xor(m, 16));
    m = fmaxf(m, __shfl_xor(m, 32));
    float e0 = __expf(s0 - m), e1 = __expf(s1 - m), e2 = __expf(s2 - m), e3 = __expf(s3 - m);
    float rs = e0 + e1 + e2 + e3;
    rs += __shfl_xor(rs, 16);
    rs += __shfl_xor(rs, 32);
    const float inv = 1.f / (rs * 16.f);
    float cb[4] = {e0 * inv, e1 * inv, e2 * inv, e3 * inv};
#pragma unroll
    for (int msk = 1; msk <= 8; msk <<= 1) {
        cb[0] += __shfl_xor(cb[0], msk);
        cb[1] += __shfl_xor(cb[1], msk);
        cb[2] += __shfl_xor(cb[2], msk);
        cb[3] += __shfl_xor(cb[3], msk);
    }
    float call[16];
#pragma unroll
    for (int j = 0; j < 16; ++j)
        call[j] = __shfl(cb[j & 3], (j >> 2) << 4);

    // y = cbar @ X : each lane 8 cols
    const int c0 = lane << 3;
    const bf16* xb = X + (long)g * 16 * 512 + c0;
    float yacc[8] = {};
#pragma unroll
    for (int j = 0; j < 16; ++j) {
        bf16x8 xv = *(const bf16x8*)(xb + (long)j * 512);
        const float cj = call[j];
#pragma unroll
        for (int e = 0; e < 8; ++e) yacc[e] += cj * (float)xv[e];
    }
    bf16x8 yv;
#pragma unroll
    for (int e = 0; e < 8; ++e) yv[e] = (bf16)yacc[e];
    *(bf16x8*)(Y + (long)g * 1024 + h * 512 + c0) = yv;
}

// q_jt = hg3 @ g_w4^T + g_b4  (4096 x 1)
__global__ void qjt_k(const bf16* __restrict__ hg, const bf16* __restrict__ w,
                      const float* __restrict__ b, float* __restrict__ out) {
    const int m = blockIdx.x * 256 + threadIdx.x;
    const bf16* hp = hg + (long)m * 256;
    float acc = 0.f;
    for (int k = 0; k < 256; k += 8) {
        bf16x8 hv = *(const bf16x8*)(hp + k);
        bf16x8 wv = *(const bf16x8*)(w + k);
#pragma unroll
        for (int e = 0; e < 8; ++e) acc += (float)hv[e] * (float)wv[e];
    }
    out[m] = acc + b[0];
}

// alt_q = hp2 @ phi2_w3^T + phi2_b3  (65536 x 2)
__global__ void altq_k(const bf16* __restrict__ hp, const bf16* __restrict__ w,
                       const float* __restrict__ b, float* __restrict__ out) {
    const int m = blockIdx.x * 256 + threadIdx.x;
    const bf16* hr = hp + (long)m * 256;
    float a0 = 0.f, a1 = 0.f;
    for (int k = 0; k < 256; k += 8) {
        bf16x8 hv = *(const bf16x8*)(hr + k);
        bf16x8 w0 = *(const bf16x8*)(w + k);
        bf16x8 w1 = *(const bf16x8*)(w + 256 + k);
#pragma unroll
        for (int e = 0; e < 8; ++e) {
            float hf = (float)hv[e];
            a0 += hf * (float)w0[e];
            a1 += hf * (float)w1[e];
        }
    }
    out[2 * m]     = a0 + b[0];
    out[2 * m + 1] = a1 + b[1];
}

// ---------------------------------------------------------------------------
extern "C" void kernel_launch(void* const* d_in, const int* in_sizes, int n_in,
                              void* d_out, int out_size, void* d_ws, size_t ws_size,
                              hipStream_t stream) {
    const float* enc    = (const float*)d_in[0];
    const float* encA   = (const float*)d_in[1];
    const float* w_ain  = (const float*)d_in[2];
    const float* b_ain  = (const float*)d_in[3];
    const float* w_aout = (const float*)d_in[4];
    const float* b_aout = (const float*)d_in[5];
    const float* w_p11  = (const float*)d_in[6];
    const float* b_p11  = (const float*)d_in[7];
    const float* w_p12  = (const float*)d_in[8];
    const float* b_p12  = (const float*)d_in[9];
    const float* w_p13  = (const float*)d_in[10];
    const float* b_p13  = (const float*)d_in[11];
    const float* w_p14  = (const float*)d_in[12];
    const float* b_p14  = (const float*)d_in[13];
    const float* w_g1   = (const float*)d_in[14];
    const float* b_g1   = (const float*)d_in[15];
    const float* w_g2   = (const float*)d_in[16];
    const float* b_g2   = (const float*)d_in[17];
    const float* w_g3   = (const float*)d_in[18];
    const float* b_g3   = (const float*)d_in[19];
    const float* w_g4   = (const float*)d_in[20];
    const float* b_g4   = (const float*)d_in[21];
    const float* w_p21  = (const float*)d_in[22];
    const float* b_p21  = (const float*)d_in[23];
    const float* w_p22  = (const float*)d_in[24];
    const float* b_p22  = (const float*)d_in[25];
    const float* w_p23  = (const float*)d_in[26];
    const float* b_p23  = (const float*)d_in[27];
    float* out = (float*)d_out;

    char* wsc = (char*)d_ws;
    size_t off = 0;
    auto take = [&](size_t bytes) -> char* {
        char* p = wsc + off;
        off += (bytes + 255) & ~(size_t)255;
        return p;
    };

    // bf16 weight region
    const long o_ain  = 0;                       // 1536x512 (only rows 0..1024 used)
    const long o_p11  = o_ain + 1536L * 512;     // 256x576 (padded)
    const long o_p12  = o_p11 + 256L * 576;
    const long o_p13  = o_p12 + 256L * 256;
    const long o_p14  = o_p13 + 256L * 256;
    const long o_g1   = o_p14 + 512L * 256;
    const long o_g2   = o_g1 + 256L * 512;
    const long o_g3   = o_g2 + 256L * 256;
    const long o_g4   = o_g3 + 256L * 256;
    const long o_p21  = o_g4 + 256L;
    const long o_p22  = o_p21 + 256L * 512;
    const long o_p23  = o_p22 + 256L * 256;
    const long o_aout = o_p23 + 2L * 256;        // unused region kept for cvt simplicity
    const long wtot   = o_aout + 512L * 512;

    bf16*  wb   = (bf16*)take((size_t)wtot * 2);
    bf16*  Ha   = (bf16*)take(65536ull * 256 * 2);
    bf16*  Hb   = (bf16*)take(65536ull * 256 * 2);
    bf16*  K1   = (bf16*)take(65536ull * 512 * 2);
    float* KM   = (float*)take(4096ull * 512 * 4);
    bf16*  HGa  = (bf16*)take(4096ull * 256 * 2);
    bf16*  HGb  = (bf16*)take(4096ull * 256 * 2);
    bf16*  Ybig = (bf16*)take(4096ull * 1024 * 2);
    bf16*  Mbig = (bf16*)take(512ull * 1024 * 2);
    float* c0v  = (float*)take(512 * 4);

    // shared region: encA-bf16 (65536x576) first, later reused as QK chunks
    const size_t acvt_bytes = 65536ull * 576 * 2;
    int CH = 16;
    const size_t rem = (ws_size > off) ? ws_size - off : 0;
    auto fits = [&](int ch) {
        size_t need = (size_t)(65536 / ch) * 1024 * 2;
        if (need < acvt_bytes) need = acvt_bytes;
        return need <= rem;
    };
    if (fits(1)) CH = 1;
    else if (fits(2)) CH = 2;
    else if (fits(4)) CH = 4;
    else if (fits(8)) CH = 8;
    bf16* SHARED = (bf16*)(wsc + off);
    bf16* Acvt = SHARED;
    bf16* QK   = SHARED;

    // ---- 1. weight cvt + precomputes ----
    CvtArgs ca;
    const float* srcs[13] = {w_ain, w_p11, w_p12, w_p13, w_p14,
                             w_g1, w_g2, w_g3, w_g4, w_p21, w_p22, w_p23, w_aout};
    const int rows_[13]  = {1536, 256, 256, 256, 512, 256, 256, 256, 1, 256, 256, 2, 512};
    const int scols_[13] = {512, 514, 256, 256, 256, 512, 256, 256, 256, 512, 256, 256, 512};
    const int dcols_[13] = {512, 576, 256, 256, 256, 512, 256, 256, 256, 512, 256, 256, 512};
    for (int s = 0; s < 13; ++s) {
        ca.src[s] = srcs[s]; ca.rows[s] = rows_[s];
        ca.scols[s] = scols_[s]; ca.dcols[s] = dcols_[s];
    }
    ca.total = (int)wtot;
    cvt_k<<<dim3((unsigned)((wtot + 255) / 256)), dim3(256), 0, stream>>>(ca, wb);
    cvtA_k<<<dim3(65536 * 72 / 256), dim3(256), 0, stream>>>(encA, Acvt);
    mbig_k<<<dim3(512), dim3(256), 0, stream>>>(w_aout, w_ain, Mbig);
    c0_k<<<dim3(4), dim3(128), 0, stream>>>(w_aout, b_ain + 1024, b_aout, c0v);

    GemmArgs ga;

    // ---- 2. phi1 chain ----
    ga = {}; ga.Ab = Acvt; ga.lda = 576; ga.W = wb + o_p11; ga.ldw = 576;
    ga.bias = b_p11; ga.Cb = Ha; ga.ldc = 256; ga.nK = 9;
    gemm_t<AM_BF16, ACT_ELU, true><<<dim3(512, 2), 256, 0, stream>>>(ga);

    ga = {}; ga.Ab = Ha; ga.lda = 256; ga.W = wb + o_p12; ga.ldw = 256;
    ga.bias = b_p12; ga.Cb = Hb; ga.ldc = 256; ga.nK = 4;
    gemm_t<AM_BF16, ACT_ELU2, true><<<dim3(512, 2), 256, 0, stream>>>(ga);

    ga = {}; ga.Ab = Hb; ga.lda = 256; ga.W = wb + o_p13; ga.ldw = 256;
    ga.bias = b_p13; ga.Cb = Ha; ga.ldc = 256; ga.nK = 4;
    gemm_t<AM_BF16, ACT_ELU, true><<<dim3(512, 2), 256, 0, stream>>>(ga);

    ga = {}; ga.Ab = Ha; ga.lda = 256; ga.W = wb + o_p14; ga.ldw = 256;
    ga.bias = b_p14; ga.Cb = K1; ga.ldc = 512; ga.nK = 4;
    gemm_t<AM_BF16, ACT_NONE, true><<<dim3(512, 4), 256, 0, stream>>>(ga);

    // ---- 3. chunked qk + attention (writes Y) ----
    const int Mc = 65536 / CH;
    const int gc = 4096 / CH;
    for (int c = 0; c < CH; ++c) {
        ga = {}; ga.Ab = K1 + (long)c * Mc * 512; ga.lda = 512;
        ga.W = wb + o_ain; ga.ldw = 512; ga.bias = b_ain;
        ga.Cb = QK; ga.ldc = 1024; ga.nK = 8;
        gemm_t<AM_BF16, ACT_NONE, true>
            <<<dim3(Mc / 128, 8), 256, 0, stream>>>(ga);
        attn_k<<<dim3(gc / 2), 256, 0, stream>>>(
            QK, K1 + (long)c * Mc * 512, Ybig + (long)c * gc * 1024, gc);
    }

    // ---- 4. key1_mean = Y @ Mbig^T + c0 (f32 out) ----
    ga = {}; ga.Ab = Ybig; ga.lda = 1024; ga.W = Mbig; ga.ldw = 1024;
    ga.bias = c0v; ga.Cf = KM; ga.ldc = 512; ga.nK = 16;
    gemm_t<AM_BF16, ACT_NONE, false><<<dim3(32, 4), 256, 0, stream>>>(ga);

    // ---- 5. g head ----
    ga = {}; ga.Af = KM; ga.lda = 512; ga.W = wb + o_g1; ga.ldw = 512;
    ga.bias = b_g1; ga.Cb = HGa; ga.ldc = 256; ga.nK = 8;
    gemm_t<AM_F32, ACT_ELU, true><<<dim3(32, 2), 256, 0, stream>>>(ga);

    ga = {}; ga.Ab = HGa; ga.lda = 256; ga.W = wb + o_g2; ga.ldw = 256;
    ga.bias = b_g2; ga.Cb = HGb; ga.ldc = 256; ga.nK = 4;
    gemm_t<AM_BF16, ACT_ELU, true><<<dim3(32, 2), 256, 0, stream>>>(ga);

    ga = {}; ga.Ab = HGb; ga.lda = 256; ga.W = wb + o_g3; ga.ldw = 256;
    ga.bias = b_g3; ga.Cb = HGa; ga.ldc = 256; ga.nK = 4;
    gemm_t<AM_BF16, ACT_ELU, true><<<dim3(32, 2), 256, 0, stream>>>(ga);

    qjt_k<<<dim3(16), 256, 0, stream>>>(HGa, wb + o_g4, b_g4, out);

    // ---- 6. phi2 chain (alt_val fused into A staging) ----
    ga = {}; ga.enc = enc; ga.km = KM; ga.key1 = K1;
    ga.W = wb + o_p21; ga.ldw = 512; ga.bias = b_p21;
    ga.Cb = Ha; ga.ldc = 256; ga.nK = 8;
    gemm_t<AM_ALT, ACT_ELU, true><<<dim3(512, 2), 256, 0, stream>>>(ga);

    ga = {}; ga.Ab = Ha; ga.lda = 256; ga.W = wb + o_p22; ga.ldw = 256;
    ga.bias = b_p22; ga.Cb = Hb; ga.ldc = 256; ga.nK = 4;
    gemm_t<AM_BF16, ACT_ELU, true><<<dim3(512, 2), 256, 0, stream>>>(ga);

    altq_k<<<dim3(256), 256, 0, stream>>>(Hb, wb + o_p23, b_p23, out + 4096);
}